// Round 25
// baseline (308.001 us; speedup 1.0000x reference)
//
#include <hip/hip_runtime.h>
#include <hip/hip_fp16.h>

// GCN 3-layer forward: x[N,128] -> GCNConv(64) -> leaky -> GCNConv(32) -> leaky
// -> GCNConv(4) -> softmax.  N=100000, E=3200000.
// Round 25: tmp record split 8B -> 6B: tmp_key uint (dlocal<<17|src, 25 bits) +
// tmp_w ushort fp16(w). Saves 2B/edge on bscatter write and both bcsr reads
// (~19MB). deg now sums fp16-rounded w (rel ~5e-4, absmax margin holds).
// Everything else identical to round 24 (294us).

#define BLK 256

typedef _Float16 f16x8 __attribute__((ext_vector_type(8)));
typedef float f32x4 __attribute__((ext_vector_type(4)));

// ---- merged: blocks [0,256) LDS-histogram dst buckets (bucket = dst>>8);
//      blocks [256,..) layer-1 linear x @ W1.T -> h1 fp16 via MFMA 16x16x32. ----
__global__ __launch_bounds__(256) void k_hist_lin1(
        const int* __restrict__ dst, int* __restrict__ hist, int E, int CH, int NB,
        const float* __restrict__ xin, const float* __restrict__ W1,
        ushort* __restrict__ outh, int n) {
    __shared__ __align__(16) char smem[64 * 136 * 2];   // 17.4 KB union
    int b = blockIdx.x, t = threadIdx.x;
    if (b < 256) {
        int* h = (int*)smem;                            // NB <= 512 counters
        for (int i = t; i < NB; i += 256) h[i] = 0;
        __syncthreads();
        int beg = b * CH, fin = min(E, beg + CH);
        for (int e = beg + t; e < fin; e += 256)
            atomicAdd(&h[dst[e] >> 8], 1);
        __syncthreads();
        for (int i = t; i < NB; i += 256) hist[i * 256 + b] = h[i];
        return;
    }
    // ---- linear1 path ----
    _Float16* sW = (_Float16*)smem;
    constexpr int WS = 136;
    for (int i = t; i < 8192; i += 256) {
        int c = i >> 7, k = i & 127;
        sW[c * WS + k] = (_Float16)W1[i];
    }
    __syncthreads();
    int w = t >> 6, l = t & 63;
    int lr = l & 15, lg = l >> 4;
    int row0 = (b - 256) * 64 + w * 16;
    if (row0 >= n) return;
    int arow = min(row0 + lr, n - 1);
    const float* xr = xin + (size_t)arow * 128 + lg * 8;

    f32x4 acc[4] = {{0.f,0.f,0.f,0.f},{0.f,0.f,0.f,0.f},
                    {0.f,0.f,0.f,0.f},{0.f,0.f,0.f,0.f}};
#pragma unroll
    for (int kt = 0; kt < 4; ++kt) {
        float4 a0 = *(const float4*)(xr + kt * 32);
        float4 a1 = *(const float4*)(xr + kt * 32 + 4);
        f16x8 af;
        af[0] = (_Float16)a0.x; af[1] = (_Float16)a0.y;
        af[2] = (_Float16)a0.z; af[3] = (_Float16)a0.w;
        af[4] = (_Float16)a1.x; af[5] = (_Float16)a1.y;
        af[6] = (_Float16)a1.z; af[7] = (_Float16)a1.w;
#pragma unroll
        for (int ct = 0; ct < 4; ++ct) {
            int c = ct * 16 + lr;
            f16x8 bf = *(const f16x8*)&sW[c * WS + kt * 32 + lg * 8];
            acc[ct] = __builtin_amdgcn_mfma_f32_16x16x32_f16(af, bf, acc[ct], 0, 0, 0);
        }
    }
#pragma unroll
    for (int ct = 0; ct < 4; ++ct) {
#pragma unroll
        for (int i = 0; i < 4; ++i) {
            int r = row0 + lg * 4 + i;
            if (r < n) outh[(size_t)r * 64 + ct * 16 + lr] =
                __half_as_ushort(__float2half(acc[ct][i]));
        }
    }
}

// ---- 2-kernel exclusive scan (partials applied at read time) ----
__global__ void k_scan1(const int* __restrict__ in, int* __restrict__ outv,
                        int* __restrict__ partials, int n) {
    __shared__ int sm[256];
    int i = blockIdx.x * 256 + threadIdx.x;
    int v = (i < n) ? in[i] : 0;
    sm[threadIdx.x] = v;
    __syncthreads();
    for (int off = 1; off < 256; off <<= 1) {
        int t = (threadIdx.x >= off) ? sm[threadIdx.x - off] : 0;
        __syncthreads();
        sm[threadIdx.x] += t;
        __syncthreads();
    }
    if (i < n) outv[i] = sm[threadIdx.x] - v;
    if (threadIdx.x == 255) partials[blockIdx.x] = sm[255];
}

__global__ void k_scan2(int* __restrict__ partials, int nb) {
    __shared__ int sm[512];
    int t = threadIdx.x;
    int v = (t < nb) ? partials[t] : 0;
    sm[t] = v;
    __syncthreads();
    for (int off = 1; off < 512; off <<= 1) {
        int x = (t >= off) ? sm[t - off] : 0;
        __syncthreads();
        sm[t] += x;
        __syncthreads();
    }
    if (t < nb) partials[t] = sm[t] - v;
}

// ---- Phase C: scatter edges into bucket-sorted tmp (key 4B + w 2B) ----
// key: (dlocal << 17) | src   (dlocal < 256, src < 2^17)
__global__ __launch_bounds__(256) void k_bscatter(const int* __restrict__ src,
                                                  const int* __restrict__ dst,
                                                  const float* __restrict__ w,
                                                  const int* __restrict__ scanout,
                                                  const int* __restrict__ partials,
                                                  uint* __restrict__ tmpk,
                                                  ushort* __restrict__ tmpw,
                                                  int E, int CH, int NB) {
    __shared__ int cur[512];
    int b = blockIdx.x, t = threadIdx.x;
    for (int i = t; i < NB; i += 256)
        cur[i] = scanout[i * 256 + b] + partials[i];
    __syncthreads();
    int beg = b * CH, fin = min(E, beg + CH);
    for (int e = beg + t; e < fin; e += 256) {
        int d = dst[e];
        int q = d >> 8;
        int pos = atomicAdd(&cur[q], 1);             // LDS atomic
        tmpk[pos] = ((uint)(d & 255) << 17) | (uint)src[e];
        tmpw[pos] = __half_as_ushort(__float2half(w[e]));
    }
}

// ---- Phase D: per-bucket CSR + fused dis; one node per thread (256/bucket) ----
// pack word (4B): (src << 15) | (fp16(norm) & 0x7FFF)
__global__ __launch_bounds__(256) void k_bcsr(const int* __restrict__ scanout,
                                              const int* __restrict__ partials,
                                              const uint* __restrict__ tmpk,
                                              const ushort* __restrict__ tmpw,
                                              uint* __restrict__ pack,
                                              int* __restrict__ row_ptr,
                                              float* __restrict__ dis,
                                              int n, int E, int NB) {
    __shared__ int cnt[256];
    __shared__ float wsum[256];
    __shared__ int psum[256];
    int q = blockIdx.x, t = threadIdx.x;
    int base = scanout[q * 256] + partials[q];
    int end  = (q == NB - 1) ? E : (scanout[(q + 1) * 256] + partials[q + 1]);
    cnt[t] = 0;
    wsum[t] = 0.f;
    __syncthreads();
    for (int j = base + t; j < end; j += 256) {
        int d = (int)(tmpk[j] >> 17);
        float wv = __half2float(__ushort_as_half(tmpw[j]));
        atomicAdd(&cnt[d], 1);
        atomicAdd(&wsum[d], wv);
    }
    __syncthreads();
    int my = cnt[t];
    psum[t] = my;
    __syncthreads();
    for (int off = 1; off < 256; off <<= 1) {
        int v = (t >= off) ? psum[t - off] : 0;
        __syncthreads();
        psum[t] += v;
        __syncthreads();
    }
    int pex = psum[t] - my;                          // exclusive prefix
    __syncthreads();
    cnt[t] = pex;                                    // fill cursor
    int node = q * 256 + t;
    if (node < n) {
        row_ptr[node] = base + pex;
        dis[node] = rsqrtf(1.f + wsum[t]);
    }
    if (q == 0 && t == 0) row_ptr[n] = E;
    __syncthreads();
    for (int j = base + t; j < end; j += 256) {
        uint k = tmpk[j];
        int d = (int)(k >> 17);
        int pos = base + atomicAdd(&cnt[d], 1);      // LDS atomic
        uint s = k & 0x1FFFF;
        pack[pos] = (s << 15) | (uint)(tmpw[j] & 0x7FFF);
    }
}

// one wave per node: pack.norm = fp16(dis[d] * w * dis[src])  (contiguous RMW)
__global__ __launch_bounds__(256) void k_norm(const int* __restrict__ rp,
                                              const float* __restrict__ dis,
                                              uint* __restrict__ pack, int n) {
    int node = blockIdx.x * 4 + (threadIdx.x >> 6);
    int lane = threadIdx.x & 63;
    if (node >= n) return;
    float dd = dis[node];
    int beg = rp[node], end = rp[node + 1];
    for (int j = beg + lane; j < end; j += 64) {
        uint p = pack[j];
        int s = (int)(p >> 15);
        float wv = __half2float(__ushort_as_half((ushort)(p & 0x7FFF)));
        float nm = dd * wv * dis[s];
        ushort nh = __half_as_ushort(__float2half(nm));
        pack[j] = (p & 0xFFFF8000u) | (uint)(nh & 0x7FFF);
    }
}

__device__ __forceinline__ float leaky01(float v) {
    return v > 0.f ? v : 0.01f * v;
}
__device__ __forceinline__ ushort f2h(float f) {
    return __half_as_ushort(__float2half(f));
}
__device__ __forceinline__ __half2 bch2(uint v) {
    union { uint u; __half2 h; } c; c.u = v; return c.h;
}
__device__ __forceinline__ float pknorm(uint p) {
    return __half2float(__ushort_as_half((ushort)(p & 0x7FFF)));
}

// layer-1 agg + leaky(+b1) + W2 matmul -> h2 fp16 [N,32].  One wave per node;
// 8-lane group es x uint4 = 8 edges/wave-instr; 4B pack words.
__global__ __launch_bounds__(256) void fgather64(
        const int* __restrict__ rp, const uint* __restrict__ pack,
        const float* __restrict__ dis, const ushort* __restrict__ h1h,
        const float* __restrict__ b1, const float* __restrict__ W2,   // [32][64]
        ushort* __restrict__ h2h, int n) {
    __shared__ float sW2t[64 * 33];    // [c][c2], padded
    __shared__ float sact[4][64];
    int tid = threadIdx.x;
    for (int i = tid; i < 2048; i += 256)
        sW2t[(i & 63) * 33 + (i >> 6)] = W2[i];
    int w = tid >> 6, l = tid & 63;
    int es = l >> 3, g = l & 7;        // edge-set 0..7, col group (cols 8g..8g+7)
    int node = blockIdx.x * 4 + w;
    bool valid = node < n;
    float acc[8] = {0.f, 0.f, 0.f, 0.f, 0.f, 0.f, 0.f, 0.f};
    if (valid) {
        int beg = rp[node], end = rp[node + 1];
        int j = beg;
        for (; j + 16 <= end; j += 16) {               // 16 edges in flight
            uint pa = pack[j + es];
            uint pb = pack[j + 8 + es];
            uint4 ua = *(const uint4*)&h1h[(size_t)(pa >> 15) * 64 + 8 * g];
            uint4 ub = *(const uint4*)&h1h[(size_t)(pb >> 15) * 64 + 8 * g];
            float na = pknorm(pa), nb2 = pknorm(pb);
            __half2 h0;
            h0 = bch2(ua.x); acc[0] = fmaf(__low2float(h0), na, acc[0]);
                             acc[1] = fmaf(__high2float(h0), na, acc[1]);
            h0 = bch2(ua.y); acc[2] = fmaf(__low2float(h0), na, acc[2]);
                             acc[3] = fmaf(__high2float(h0), na, acc[3]);
            h0 = bch2(ua.z); acc[4] = fmaf(__low2float(h0), na, acc[4]);
                             acc[5] = fmaf(__high2float(h0), na, acc[5]);
            h0 = bch2(ua.w); acc[6] = fmaf(__low2float(h0), na, acc[6]);
                             acc[7] = fmaf(__high2float(h0), na, acc[7]);
            h0 = bch2(ub.x); acc[0] = fmaf(__low2float(h0), nb2, acc[0]);
                             acc[1] = fmaf(__high2float(h0), nb2, acc[1]);
            h0 = bch2(ub.y); acc[2] = fmaf(__low2float(h0), nb2, acc[2]);
                             acc[3] = fmaf(__high2float(h0), nb2, acc[3]);
            h0 = bch2(ub.z); acc[4] = fmaf(__low2float(h0), nb2, acc[4]);
                             acc[5] = fmaf(__high2float(h0), nb2, acc[5]);
            h0 = bch2(ub.w); acc[6] = fmaf(__low2float(h0), nb2, acc[6]);
                             acc[7] = fmaf(__high2float(h0), nb2, acc[7]);
        }
        for (; j < end; j += 8) {
            if (j + es < end) {
                uint p = pack[j + es];
                uint4 u = *(const uint4*)&h1h[(size_t)(p >> 15) * 64 + 8 * g];
                float nm = pknorm(p);
                __half2 h0;
                h0 = bch2(u.x); acc[0] = fmaf(__low2float(h0), nm, acc[0]);
                                acc[1] = fmaf(__high2float(h0), nm, acc[1]);
                h0 = bch2(u.y); acc[2] = fmaf(__low2float(h0), nm, acc[2]);
                                acc[3] = fmaf(__high2float(h0), nm, acc[3]);
                h0 = bch2(u.z); acc[4] = fmaf(__low2float(h0), nm, acc[4]);
                                acc[5] = fmaf(__high2float(h0), nm, acc[5]);
                h0 = bch2(u.w); acc[6] = fmaf(__low2float(h0), nm, acc[6]);
                                acc[7] = fmaf(__high2float(h0), nm, acc[7]);
            }
        }
#pragma unroll
        for (int u = 0; u < 8; ++u) {
            acc[u] += __shfl_xor(acc[u], 8);
            acc[u] += __shfl_xor(acc[u], 16);
            acc[u] += __shfl_xor(acc[u], 32);
        }
        if (es == 0) {                                  // self-loop + bias
            float dd = dis[node], d2 = dd * dd;
            uint4 u = *(const uint4*)&h1h[(size_t)node * 64 + 8 * g];
            __half2 h0;
            h0 = bch2(u.x); acc[0] = fmaf(__low2float(h0), d2, acc[0]);
                            acc[1] = fmaf(__high2float(h0), d2, acc[1]);
            h0 = bch2(u.y); acc[2] = fmaf(__low2float(h0), d2, acc[2]);
                            acc[3] = fmaf(__high2float(h0), d2, acc[3]);
            h0 = bch2(u.z); acc[4] = fmaf(__low2float(h0), d2, acc[4]);
                            acc[5] = fmaf(__high2float(h0), d2, acc[5]);
            h0 = bch2(u.w); acc[6] = fmaf(__low2float(h0), d2, acc[6]);
                            acc[7] = fmaf(__high2float(h0), d2, acc[7]);
#pragma unroll
            for (int u2 = 0; u2 < 8; ++u2)
                sact[w][8 * g + u2] = leaky01(acc[u2] + b1[8 * g + u2]);
        }
    }
    __syncthreads();
    if (valid) {
        int c2 = l & 31, half = l >> 5;
        float s = 0.f;
#pragma unroll 8
        for (int cc = 0; cc < 32; ++cc) {
            int c = half * 32 + cc;
            s += sW2t[c * 33 + c2] * sact[w][c];
        }
        s += __shfl_xor(s, 32);
        if (l < 32) h2h[(size_t)node * 32 + c2] = f2h(s);
    }
}

// layer-2 agg + leaky(+b2) + W3 matmul -> h3 f32 [N,4].  One wave per node;
// 8-lane group es x uint2 (cols 4g..4g+3); 4B pack words.
__global__ __launch_bounds__(256) void fgather32(
        const int* __restrict__ rp, const uint* __restrict__ pack,
        const float* __restrict__ dis, const ushort* __restrict__ h2h,
        const float* __restrict__ b2, const float* __restrict__ W3,   // [4][32]
        float* __restrict__ h3out, int n) {
    __shared__ float sW3t[32 * 5];     // [c][c3], padded
    __shared__ float sact[4][32];
    int tid = threadIdx.x;
    if (tid < 128) sW3t[(tid & 31) * 5 + (tid >> 5)] = W3[tid];
    int w = tid >> 6, l = tid & 63;
    int es = l >> 3, g = l & 7;        // cols 4g..4g+3
    int node = blockIdx.x * 4 + w;
    bool valid = node < n;
    float acc[4] = {0.f, 0.f, 0.f, 0.f};
    if (valid) {
        int beg = rp[node], end = rp[node + 1];
        int j = beg;
        for (; j + 16 <= end; j += 16) {               // 16 edges in flight
            uint pa = pack[j + es];
            uint pb = pack[j + 8 + es];
            uint2 ua = *(const uint2*)&h2h[(size_t)(pa >> 15) * 32 + 4 * g];
            uint2 ub = *(const uint2*)&h2h[(size_t)(pb >> 15) * 32 + 4 * g];
            float na = pknorm(pa), nb2 = pknorm(pb);
            __half2 h0;
            h0 = bch2(ua.x); acc[0] = fmaf(__low2float(h0), na, acc[0]);
                             acc[1] = fmaf(__high2float(h0), na, acc[1]);
            h0 = bch2(ua.y); acc[2] = fmaf(__low2float(h0), na, acc[2]);
                             acc[3] = fmaf(__high2float(h0), na, acc[3]);
            h0 = bch2(ub.x); acc[0] = fmaf(__low2float(h0), nb2, acc[0]);
                             acc[1] = fmaf(__high2float(h0), nb2, acc[1]);
            h0 = bch2(ub.y); acc[2] = fmaf(__low2float(h0), nb2, acc[2]);
                             acc[3] = fmaf(__high2float(h0), nb2, acc[3]);
        }
        for (; j < end; j += 8) {
            if (j + es < end) {
                uint p = pack[j + es];
                uint2 u = *(const uint2*)&h2h[(size_t)(p >> 15) * 32 + 4 * g];
                float nm = pknorm(p);
                __half2 h0;
                h0 = bch2(u.x); acc[0] = fmaf(__low2float(h0), nm, acc[0]);
                                acc[1] = fmaf(__high2float(h0), nm, acc[1]);
                h0 = bch2(u.y); acc[2] = fmaf(__low2float(h0), nm, acc[2]);
                                acc[3] = fmaf(__high2float(h0), nm, acc[3]);
            }
        }
#pragma unroll
        for (int u = 0; u < 4; ++u) {
            acc[u] += __shfl_xor(acc[u], 8);
            acc[u] += __shfl_xor(acc[u], 16);
            acc[u] += __shfl_xor(acc[u], 32);
        }
        if (es == 0) {
            float dd = dis[node], d2 = dd * dd;
            uint2 u = *(const uint2*)&h2h[(size_t)node * 32 + 4 * g];
            __half2 h0;
            h0 = bch2(u.x); acc[0] = fmaf(__low2float(h0), d2, acc[0]);
                            acc[1] = fmaf(__high2float(h0), d2, acc[1]);
            h0 = bch2(u.y); acc[2] = fmaf(__low2float(h0), d2, acc[2]);
                            acc[3] = fmaf(__high2float(h0), d2, acc[3]);
#pragma unroll
            for (int u2 = 0; u2 < 4; ++u2)
                sact[w][4 * g + u2] = leaky01(acc[u2] + b2[4 * g + u2]);
        }
    }
    __syncthreads();
    if (valid && l < 32) {
        int c3 = l & 3;
        float s = 0.f;
#pragma unroll
        for (int m = 0; m < 4; ++m) {
            int c = (l >> 2) + 8 * m;
            s += sW3t[c * 5 + c3] * sact[w][c];
        }
        s += __shfl_xor(s, 4, 32);
        s += __shfl_xor(s, 8, 32);
        s += __shfl_xor(s, 16, 32);
        if (l < 4) h3out[(size_t)node * 4 + l] = s;
    }
}

// layer-3 agg + b3 + softmax -> out[N,4].  32-lane group per node; lane j owns
// edge beg+j and loads the full 16B h3 row as float4; xor-tree reduce.
__global__ __launch_bounds__(256) void fgather4(
        const int* __restrict__ rp, const uint* __restrict__ pack,
        const float* __restrict__ dis, const float* __restrict__ h3,
        const float* __restrict__ b3, float* __restrict__ out, int n) {
    int tid = threadIdx.x;
    int node = blockIdx.x * 8 + (tid >> 5);
    int l32 = tid & 31;
    if (node >= n) return;
    int beg = rp[node], end = rp[node + 1];
    float4 acc = make_float4(0.f, 0.f, 0.f, 0.f);
    for (int j = beg + l32; j < end; j += 32) {
        uint p = pack[j];
        float4 hr = *(const float4*)&h3[(size_t)(p >> 15) * 4];
        float nm = pknorm(p);
        acc.x += nm * hr.x; acc.y += nm * hr.y;
        acc.z += nm * hr.z; acc.w += nm * hr.w;
    }
#pragma unroll
    for (int off = 1; off <= 16; off <<= 1) {
        acc.x += __shfl_xor(acc.x, off, 32);
        acc.y += __shfl_xor(acc.y, off, 32);
        acc.z += __shfl_xor(acc.z, off, 32);
        acc.w += __shfl_xor(acc.w, off, 32);
    }
    if (l32 == 0) {
        float dd = dis[node], d2 = dd * dd;
        float4 hr = *(const float4*)&h3[(size_t)node * 4];
        float v0 = acc.x + d2 * hr.x + b3[0];
        float v1 = acc.y + d2 * hr.y + b3[1];
        float v2 = acc.z + d2 * hr.z + b3[2];
        float v3 = acc.w + d2 * hr.w + b3[3];
        float m = fmaxf(fmaxf(v0, v1), fmaxf(v2, v3));
        float e0 = expf(v0 - m), e1 = expf(v1 - m);
        float e2 = expf(v2 - m), e3 = expf(v3 - m);
        float inv = 1.f / (e0 + e1 + e2 + e3);
        *(float4*)&out[(size_t)node * 4] =
            make_float4(e0 * inv, e1 * inv, e2 * inv, e3 * inv);
    }
}

static inline int cdiv(long long a, int b) { return (int)((a + b - 1) / b); }

extern "C" void kernel_launch(void* const* d_in, const int* in_sizes, int n_in,
                              void* d_out, int out_size, void* d_ws, size_t ws_size,
                              hipStream_t stream) {
    const float* x   = (const float*)d_in[0];
    const int*   ei  = (const int*)d_in[1];
    const float* ew  = (const float*)d_in[2];
    const float* W1  = (const float*)d_in[3];
    const float* b1  = (const float*)d_in[4];
    const float* W2  = (const float*)d_in[5];
    const float* b2  = (const float*)d_in[6];
    const float* W3  = (const float*)d_in[7];
    const float* b3  = (const float*)d_in[8];
    float* out = (float*)d_out;

    const int N = in_sizes[0] / 128;
    const int E = in_sizes[2];
    const int* src = ei;
    const int* dst = ei + E;

    const int NB = (N + 255) >> 8;          // 391 buckets of 256 nodes
    const int GB = 256;
    const int CH = cdiv(E, GB);
    const int n_scan = NB * GB;             // 100,096

    char* base = (char*)d_ws;
    auto alloc = [&](size_t bytes) {
        char* p = base;
        base += (bytes + 255) & ~(size_t)255;
        return p;
    };
    float* dis      = (float*)alloc((size_t)N * 4);
    int*   row_ptr  = (int*)  alloc(((size_t)N + 1) * 4);
    int*   hist     = (int*)  alloc((size_t)n_scan * 4);
    int*   scanout  = (int*)  alloc((size_t)n_scan * 4);
    int*   partials = (int*)  alloc(512 * 4);
    uint*  pack     = (uint*) alloc((size_t)E * 4);
    char*  regA     = alloc((size_t)N * 64 * 4);   // tmpk+tmpw -> h3(f32)
    char*  regB     = alloc((size_t)N * 64 * 4);   // h2h (lo half) + h1h (hi half)
    uint*   tmpk = (uint*)regA;                    // [E] 4B keys
    ushort* tmpw = (ushort*)(regA + (size_t)E * 4);// [E] 2B fp16 weights
    float*  h3  = (float*)regA;                    // reuses regA after build
    ushort* h2h = (ushort*)regB;                   // [N,32] fp16, 6.4MB
    ushort* h1h = (ushort*)(regB + (size_t)N * 64 * 2);  // [N,64] fp16, upper half

    // --- merged hist + linear1 (independent of CSR build) ---
    k_hist_lin1<<<256 + cdiv(N, 64), 256, 0, stream>>>(
        dst, hist, E, CH, NB, x, W1, h1h, N);
    // --- CSR build via bucket sort ---
    k_scan1<<<cdiv(n_scan, 256), 256, 0, stream>>>(hist, scanout, partials, n_scan);
    k_scan2<<<1, 512, 0, stream>>>(partials, cdiv(n_scan, 256));
    k_bscatter<<<GB, 256, 0, stream>>>(src, dst, ew, scanout, partials,
                                       tmpk, tmpw, E, CH, NB);
    k_bcsr<<<NB, 256, 0, stream>>>(scanout, partials, tmpk, tmpw, pack,
                                   row_ptr, dis, N, E, NB);
    k_norm<<<cdiv(N, 4), 256, 0, stream>>>(row_ptr, dis, pack, N);

    // --- fused layers (h1/h2 fp16, h3 f32) ---
    fgather64<<<cdiv(N, 4), 256, 0, stream>>>(row_ptr, pack, dis, h1h, b1, W2, h2h, N);
    fgather32<<<cdiv(N, 4), 256, 0, stream>>>(row_ptr, pack, dis, h2h, b2, W3, h3, N);
    fgather4<<<cdiv(N, 8), 256, 0, stream>>>(row_ptr, pack, dis, h3, b3, out, N);
}

// Round 26
// 293.606 us; speedup vs baseline: 1.0490x; 1.0490x over previous
//
#include <hip/hip_runtime.h>
#include <hip/hip_fp16.h>

// GCN 3-layer forward: x[N,128] -> GCNConv(64) -> leaky -> GCNConv(32) -> leaky
// -> GCNConv(4) -> softmax.  N=100000, E=3200000.
// Round 26: EXACT REVERT to round-24 (294us). Round-25's split tmp (4B+2B) made
// k_bscatter do two scattered stores per edge; the 2B stores write-amplified
// 6.4MB -> 137MB (103us, 10% occupancy). Lesson: scattered stores must stay
// >=4B and single-instruction. This is the r24 bucket-256 configuration.

#define BLK 256

typedef _Float16 f16x8 __attribute__((ext_vector_type(8)));
typedef float f32x4 __attribute__((ext_vector_type(4)));

// ---- merged: blocks [0,256) LDS-histogram dst buckets (bucket = dst>>8);
//      blocks [256,..) layer-1 linear x @ W1.T -> h1 fp16 via MFMA 16x16x32. ----
__global__ __launch_bounds__(256) void k_hist_lin1(
        const int* __restrict__ dst, int* __restrict__ hist, int E, int CH, int NB,
        const float* __restrict__ xin, const float* __restrict__ W1,
        ushort* __restrict__ outh, int n) {
    __shared__ __align__(16) char smem[64 * 136 * 2];   // 17.4 KB union
    int b = blockIdx.x, t = threadIdx.x;
    if (b < 256) {
        int* h = (int*)smem;                            // NB <= 512 counters
        for (int i = t; i < NB; i += 256) h[i] = 0;
        __syncthreads();
        int beg = b * CH, fin = min(E, beg + CH);
        for (int e = beg + t; e < fin; e += 256)
            atomicAdd(&h[dst[e] >> 8], 1);
        __syncthreads();
        for (int i = t; i < NB; i += 256) hist[i * 256 + b] = h[i];
        return;
    }
    // ---- linear1 path ----
    _Float16* sW = (_Float16*)smem;
    constexpr int WS = 136;
    for (int i = t; i < 8192; i += 256) {
        int c = i >> 7, k = i & 127;
        sW[c * WS + k] = (_Float16)W1[i];
    }
    __syncthreads();
    int w = t >> 6, l = t & 63;
    int lr = l & 15, lg = l >> 4;
    int row0 = (b - 256) * 64 + w * 16;
    if (row0 >= n) return;
    int arow = min(row0 + lr, n - 1);
    const float* xr = xin + (size_t)arow * 128 + lg * 8;

    f32x4 acc[4] = {{0.f,0.f,0.f,0.f},{0.f,0.f,0.f,0.f},
                    {0.f,0.f,0.f,0.f},{0.f,0.f,0.f,0.f}};
#pragma unroll
    for (int kt = 0; kt < 4; ++kt) {
        float4 a0 = *(const float4*)(xr + kt * 32);
        float4 a1 = *(const float4*)(xr + kt * 32 + 4);
        f16x8 af;
        af[0] = (_Float16)a0.x; af[1] = (_Float16)a0.y;
        af[2] = (_Float16)a0.z; af[3] = (_Float16)a0.w;
        af[4] = (_Float16)a1.x; af[5] = (_Float16)a1.y;
        af[6] = (_Float16)a1.z; af[7] = (_Float16)a1.w;
#pragma unroll
        for (int ct = 0; ct < 4; ++ct) {
            int c = ct * 16 + lr;
            f16x8 bf = *(const f16x8*)&sW[c * WS + kt * 32 + lg * 8];
            acc[ct] = __builtin_amdgcn_mfma_f32_16x16x32_f16(af, bf, acc[ct], 0, 0, 0);
        }
    }
#pragma unroll
    for (int ct = 0; ct < 4; ++ct) {
#pragma unroll
        for (int i = 0; i < 4; ++i) {
            int r = row0 + lg * 4 + i;
            if (r < n) outh[(size_t)r * 64 + ct * 16 + lr] =
                __half_as_ushort(__float2half(acc[ct][i]));
        }
    }
}

// ---- 2-kernel exclusive scan (partials applied at read time) ----
__global__ void k_scan1(const int* __restrict__ in, int* __restrict__ outv,
                        int* __restrict__ partials, int n) {
    __shared__ int sm[256];
    int i = blockIdx.x * 256 + threadIdx.x;
    int v = (i < n) ? in[i] : 0;
    sm[threadIdx.x] = v;
    __syncthreads();
    for (int off = 1; off < 256; off <<= 1) {
        int t = (threadIdx.x >= off) ? sm[threadIdx.x - off] : 0;
        __syncthreads();
        sm[threadIdx.x] += t;
        __syncthreads();
    }
    if (i < n) outv[i] = sm[threadIdx.x] - v;
    if (threadIdx.x == 255) partials[blockIdx.x] = sm[255];
}

__global__ void k_scan2(int* __restrict__ partials, int nb) {
    __shared__ int sm[512];
    int t = threadIdx.x;
    int v = (t < nb) ? partials[t] : 0;
    sm[t] = v;
    __syncthreads();
    for (int off = 1; off < 512; off <<= 1) {
        int x = (t >= off) ? sm[t - off] : 0;
        __syncthreads();
        sm[t] += x;
        __syncthreads();
    }
    if (t < nb) partials[t] = sm[t] - v;
}

// ---- Phase C: scatter edges into bucket-sorted tmp ----
// record: x = (dlocal<<18) | src  (dlocal < 256, src < 2^17), y = w bits (f32)
__global__ __launch_bounds__(256) void k_bscatter(const int* __restrict__ src,
                                                  const int* __restrict__ dst,
                                                  const float* __restrict__ w,
                                                  const int* __restrict__ scanout,
                                                  const int* __restrict__ partials,
                                                  int2* __restrict__ tmp,
                                                  int E, int CH, int NB) {
    __shared__ int cur[512];
    int b = blockIdx.x, t = threadIdx.x;
    for (int i = t; i < NB; i += 256)
        cur[i] = scanout[i * 256 + b] + partials[i];
    __syncthreads();
    int beg = b * CH, fin = min(E, beg + CH);
    for (int e = beg + t; e < fin; e += 256) {
        int d = dst[e];
        int q = d >> 8;
        int pos = atomicAdd(&cur[q], 1);             // LDS atomic
        tmp[pos] = make_int2(((d & 255) << 18) | src[e], __float_as_int(w[e]));
    }
}

// ---- Phase D: per-bucket CSR + fused dis; one node per thread (256/bucket) ----
// pack word (4B): (src << 15) | (fp16(norm) & 0x7FFF)
__global__ __launch_bounds__(256) void k_bcsr(const int* __restrict__ scanout,
                                              const int* __restrict__ partials,
                                              const int2* __restrict__ tmp,
                                              uint* __restrict__ pack,
                                              int* __restrict__ row_ptr,
                                              float* __restrict__ dis,
                                              int n, int E, int NB) {
    __shared__ int cnt[256];
    __shared__ float wsum[256];
    __shared__ int psum[256];
    int q = blockIdx.x, t = threadIdx.x;
    int base = scanout[q * 256] + partials[q];
    int end  = (q == NB - 1) ? E : (scanout[(q + 1) * 256] + partials[q + 1]);
    cnt[t] = 0;
    wsum[t] = 0.f;
    __syncthreads();
    for (int j = base + t; j < end; j += 256) {
        int2 r = tmp[j];
        int d = r.x >> 18;
        atomicAdd(&cnt[d], 1);
        atomicAdd(&wsum[d], __int_as_float(r.y));
    }
    __syncthreads();
    int my = cnt[t];
    psum[t] = my;
    __syncthreads();
    for (int off = 1; off < 256; off <<= 1) {
        int v = (t >= off) ? psum[t - off] : 0;
        __syncthreads();
        psum[t] += v;
        __syncthreads();
    }
    int pex = psum[t] - my;                          // exclusive prefix
    __syncthreads();
    cnt[t] = pex;                                    // fill cursor
    int node = q * 256 + t;
    if (node < n) {
        row_ptr[node] = base + pex;
        dis[node] = rsqrtf(1.f + wsum[t]);
    }
    if (q == 0 && t == 0) row_ptr[n] = E;
    __syncthreads();
    for (int j = base + t; j < end; j += 256) {
        int2 r = tmp[j];
        int d = r.x >> 18;
        int pos = base + atomicAdd(&cnt[d], 1);      // LDS atomic
        uint s = (uint)(r.x & 0x3FFFF);
        ushort wh = __half_as_ushort(__float2half(__int_as_float(r.y)));
        pack[pos] = (s << 15) | (uint)(wh & 0x7FFF);
    }
}

// one wave per node: pack.norm = fp16(dis[d] * w * dis[src])  (contiguous RMW)
__global__ __launch_bounds__(256) void k_norm(const int* __restrict__ rp,
                                              const float* __restrict__ dis,
                                              uint* __restrict__ pack, int n) {
    int node = blockIdx.x * 4 + (threadIdx.x >> 6);
    int lane = threadIdx.x & 63;
    if (node >= n) return;
    float dd = dis[node];
    int beg = rp[node], end = rp[node + 1];
    for (int j = beg + lane; j < end; j += 64) {
        uint p = pack[j];
        int s = (int)(p >> 15);
        float wv = __half2float(__ushort_as_half((ushort)(p & 0x7FFF)));
        float nm = dd * wv * dis[s];
        ushort nh = __half_as_ushort(__float2half(nm));
        pack[j] = (p & 0xFFFF8000u) | (uint)(nh & 0x7FFF);
    }
}

__device__ __forceinline__ float leaky01(float v) {
    return v > 0.f ? v : 0.01f * v;
}
__device__ __forceinline__ ushort f2h(float f) {
    return __half_as_ushort(__float2half(f));
}
__device__ __forceinline__ __half2 bch2(uint v) {
    union { uint u; __half2 h; } c; c.u = v; return c.h;
}
__device__ __forceinline__ float pknorm(uint p) {
    return __half2float(__ushort_as_half((ushort)(p & 0x7FFF)));
}

// layer-1 agg + leaky(+b1) + W2 matmul -> h2 fp16 [N,32].  One wave per node;
// 8-lane group es x uint4 = 8 edges/wave-instr; 4B pack words.
__global__ __launch_bounds__(256) void fgather64(
        const int* __restrict__ rp, const uint* __restrict__ pack,
        const float* __restrict__ dis, const ushort* __restrict__ h1h,
        const float* __restrict__ b1, const float* __restrict__ W2,   // [32][64]
        ushort* __restrict__ h2h, int n) {
    __shared__ float sW2t[64 * 33];    // [c][c2], padded
    __shared__ float sact[4][64];
    int tid = threadIdx.x;
    for (int i = tid; i < 2048; i += 256)
        sW2t[(i & 63) * 33 + (i >> 6)] = W2[i];
    int w = tid >> 6, l = tid & 63;
    int es = l >> 3, g = l & 7;        // edge-set 0..7, col group (cols 8g..8g+7)
    int node = blockIdx.x * 4 + w;
    bool valid = node < n;
    float acc[8] = {0.f, 0.f, 0.f, 0.f, 0.f, 0.f, 0.f, 0.f};
    if (valid) {
        int beg = rp[node], end = rp[node + 1];
        int j = beg;
        for (; j + 16 <= end; j += 16) {               // 16 edges in flight
            uint pa = pack[j + es];
            uint pb = pack[j + 8 + es];
            uint4 ua = *(const uint4*)&h1h[(size_t)(pa >> 15) * 64 + 8 * g];
            uint4 ub = *(const uint4*)&h1h[(size_t)(pb >> 15) * 64 + 8 * g];
            float na = pknorm(pa), nb2 = pknorm(pb);
            __half2 h0;
            h0 = bch2(ua.x); acc[0] = fmaf(__low2float(h0), na, acc[0]);
                             acc[1] = fmaf(__high2float(h0), na, acc[1]);
            h0 = bch2(ua.y); acc[2] = fmaf(__low2float(h0), na, acc[2]);
                             acc[3] = fmaf(__high2float(h0), na, acc[3]);
            h0 = bch2(ua.z); acc[4] = fmaf(__low2float(h0), na, acc[4]);
                             acc[5] = fmaf(__high2float(h0), na, acc[5]);
            h0 = bch2(ua.w); acc[6] = fmaf(__low2float(h0), na, acc[6]);
                             acc[7] = fmaf(__high2float(h0), na, acc[7]);
            h0 = bch2(ub.x); acc[0] = fmaf(__low2float(h0), nb2, acc[0]);
                             acc[1] = fmaf(__high2float(h0), nb2, acc[1]);
            h0 = bch2(ub.y); acc[2] = fmaf(__low2float(h0), nb2, acc[2]);
                             acc[3] = fmaf(__high2float(h0), nb2, acc[3]);
            h0 = bch2(ub.z); acc[4] = fmaf(__low2float(h0), nb2, acc[4]);
                             acc[5] = fmaf(__high2float(h0), nb2, acc[5]);
            h0 = bch2(ub.w); acc[6] = fmaf(__low2float(h0), nb2, acc[6]);
                             acc[7] = fmaf(__high2float(h0), nb2, acc[7]);
        }
        for (; j < end; j += 8) {
            if (j + es < end) {
                uint p = pack[j + es];
                uint4 u = *(const uint4*)&h1h[(size_t)(p >> 15) * 64 + 8 * g];
                float nm = pknorm(p);
                __half2 h0;
                h0 = bch2(u.x); acc[0] = fmaf(__low2float(h0), nm, acc[0]);
                                acc[1] = fmaf(__high2float(h0), nm, acc[1]);
                h0 = bch2(u.y); acc[2] = fmaf(__low2float(h0), nm, acc[2]);
                                acc[3] = fmaf(__high2float(h0), nm, acc[3]);
                h0 = bch2(u.z); acc[4] = fmaf(__low2float(h0), nm, acc[4]);
                                acc[5] = fmaf(__high2float(h0), nm, acc[5]);
                h0 = bch2(u.w); acc[6] = fmaf(__low2float(h0), nm, acc[6]);
                                acc[7] = fmaf(__high2float(h0), nm, acc[7]);
            }
        }
#pragma unroll
        for (int u = 0; u < 8; ++u) {
            acc[u] += __shfl_xor(acc[u], 8);
            acc[u] += __shfl_xor(acc[u], 16);
            acc[u] += __shfl_xor(acc[u], 32);
        }
        if (es == 0) {                                  // self-loop + bias
            float dd = dis[node], d2 = dd * dd;
            uint4 u = *(const uint4*)&h1h[(size_t)node * 64 + 8 * g];
            __half2 h0;
            h0 = bch2(u.x); acc[0] = fmaf(__low2float(h0), d2, acc[0]);
                            acc[1] = fmaf(__high2float(h0), d2, acc[1]);
            h0 = bch2(u.y); acc[2] = fmaf(__low2float(h0), d2, acc[2]);
                            acc[3] = fmaf(__high2float(h0), d2, acc[3]);
            h0 = bch2(u.z); acc[4] = fmaf(__low2float(h0), d2, acc[4]);
                            acc[5] = fmaf(__high2float(h0), d2, acc[5]);
            h0 = bch2(u.w); acc[6] = fmaf(__low2float(h0), d2, acc[6]);
                            acc[7] = fmaf(__high2float(h0), d2, acc[7]);
#pragma unroll
            for (int u2 = 0; u2 < 8; ++u2)
                sact[w][8 * g + u2] = leaky01(acc[u2] + b1[8 * g + u2]);
        }
    }
    __syncthreads();
    if (valid) {
        int c2 = l & 31, half = l >> 5;
        float s = 0.f;
#pragma unroll 8
        for (int cc = 0; cc < 32; ++cc) {
            int c = half * 32 + cc;
            s += sW2t[c * 33 + c2] * sact[w][c];
        }
        s += __shfl_xor(s, 32);
        if (l < 32) h2h[(size_t)node * 32 + c2] = f2h(s);
    }
}

// layer-2 agg + leaky(+b2) + W3 matmul -> h3 f32 [N,4].  One wave per node;
// 8-lane group es x uint2 (cols 4g..4g+3); 4B pack words.
__global__ __launch_bounds__(256) void fgather32(
        const int* __restrict__ rp, const uint* __restrict__ pack,
        const float* __restrict__ dis, const ushort* __restrict__ h2h,
        const float* __restrict__ b2, const float* __restrict__ W3,   // [4][32]
        float* __restrict__ h3out, int n) {
    __shared__ float sW3t[32 * 5];     // [c][c3], padded
    __shared__ float sact[4][32];
    int tid = threadIdx.x;
    if (tid < 128) sW3t[(tid & 31) * 5 + (tid >> 5)] = W3[tid];
    int w = tid >> 6, l = tid & 63;
    int es = l >> 3, g = l & 7;        // cols 4g..4g+3
    int node = blockIdx.x * 4 + w;
    bool valid = node < n;
    float acc[4] = {0.f, 0.f, 0.f, 0.f};
    if (valid) {
        int beg = rp[node], end = rp[node + 1];
        int j = beg;
        for (; j + 16 <= end; j += 16) {               // 16 edges in flight
            uint pa = pack[j + es];
            uint pb = pack[j + 8 + es];
            uint2 ua = *(const uint2*)&h2h[(size_t)(pa >> 15) * 32 + 4 * g];
            uint2 ub = *(const uint2*)&h2h[(size_t)(pb >> 15) * 32 + 4 * g];
            float na = pknorm(pa), nb2 = pknorm(pb);
            __half2 h0;
            h0 = bch2(ua.x); acc[0] = fmaf(__low2float(h0), na, acc[0]);
                             acc[1] = fmaf(__high2float(h0), na, acc[1]);
            h0 = bch2(ua.y); acc[2] = fmaf(__low2float(h0), na, acc[2]);
                             acc[3] = fmaf(__high2float(h0), na, acc[3]);
            h0 = bch2(ub.x); acc[0] = fmaf(__low2float(h0), nb2, acc[0]);
                             acc[1] = fmaf(__high2float(h0), nb2, acc[1]);
            h0 = bch2(ub.y); acc[2] = fmaf(__low2float(h0), nb2, acc[2]);
                             acc[3] = fmaf(__high2float(h0), nb2, acc[3]);
        }
        for (; j < end; j += 8) {
            if (j + es < end) {
                uint p = pack[j + es];
                uint2 u = *(const uint2*)&h2h[(size_t)(p >> 15) * 32 + 4 * g];
                float nm = pknorm(p);
                __half2 h0;
                h0 = bch2(u.x); acc[0] = fmaf(__low2float(h0), nm, acc[0]);
                                acc[1] = fmaf(__high2float(h0), nm, acc[1]);
                h0 = bch2(u.y); acc[2] = fmaf(__low2float(h0), nm, acc[2]);
                                acc[3] = fmaf(__high2float(h0), nm, acc[3]);
            }
        }
#pragma unroll
        for (int u = 0; u < 4; ++u) {
            acc[u] += __shfl_xor(acc[u], 8);
            acc[u] += __shfl_xor(acc[u], 16);
            acc[u] += __shfl_xor(acc[u], 32);
        }
        if (es == 0) {
            float dd = dis[node], d2 = dd * dd;
            uint2 u = *(const uint2*)&h2h[(size_t)node * 32 + 4 * g];
            __half2 h0;
            h0 = bch2(u.x); acc[0] = fmaf(__low2float(h0), d2, acc[0]);
                            acc[1] = fmaf(__high2float(h0), d2, acc[1]);
            h0 = bch2(u.y); acc[2] = fmaf(__low2float(h0), d2, acc[2]);
                            acc[3] = fmaf(__high2float(h0), d2, acc[3]);
#pragma unroll
            for (int u2 = 0; u2 < 4; ++u2)
                sact[w][4 * g + u2] = leaky01(acc[u2] + b2[4 * g + u2]);
        }
    }
    __syncthreads();
    if (valid && l < 32) {
        int c3 = l & 3;
        float s = 0.f;
#pragma unroll
        for (int m = 0; m < 4; ++m) {
            int c = (l >> 2) + 8 * m;
            s += sW3t[c * 5 + c3] * sact[w][c];
        }
        s += __shfl_xor(s, 4, 32);
        s += __shfl_xor(s, 8, 32);
        s += __shfl_xor(s, 16, 32);
        if (l < 4) h3out[(size_t)node * 4 + l] = s;
    }
}

// layer-3 agg + b3 + softmax -> out[N,4].  32-lane group per node; lane j owns
// edge beg+j and loads the full 16B h3 row as float4; xor-tree reduce.
__global__ __launch_bounds__(256) void fgather4(
        const int* __restrict__ rp, const uint* __restrict__ pack,
        const float* __restrict__ dis, const float* __restrict__ h3,
        const float* __restrict__ b3, float* __restrict__ out, int n) {
    int tid = threadIdx.x;
    int node = blockIdx.x * 8 + (tid >> 5);
    int l32 = tid & 31;
    if (node >= n) return;
    int beg = rp[node], end = rp[node + 1];
    float4 acc = make_float4(0.f, 0.f, 0.f, 0.f);
    for (int j = beg + l32; j < end; j += 32) {
        uint p = pack[j];
        float4 hr = *(const float4*)&h3[(size_t)(p >> 15) * 4];
        float nm = pknorm(p);
        acc.x += nm * hr.x; acc.y += nm * hr.y;
        acc.z += nm * hr.z; acc.w += nm * hr.w;
    }
#pragma unroll
    for (int off = 1; off <= 16; off <<= 1) {
        acc.x += __shfl_xor(acc.x, off, 32);
        acc.y += __shfl_xor(acc.y, off, 32);
        acc.z += __shfl_xor(acc.z, off, 32);
        acc.w += __shfl_xor(acc.w, off, 32);
    }
    if (l32 == 0) {
        float dd = dis[node], d2 = dd * dd;
        float4 hr = *(const float4*)&h3[(size_t)node * 4];
        float v0 = acc.x + d2 * hr.x + b3[0];
        float v1 = acc.y + d2 * hr.y + b3[1];
        float v2 = acc.z + d2 * hr.z + b3[2];
        float v3 = acc.w + d2 * hr.w + b3[3];
        float m = fmaxf(fmaxf(v0, v1), fmaxf(v2, v3));
        float e0 = expf(v0 - m), e1 = expf(v1 - m);
        float e2 = expf(v2 - m), e3 = expf(v3 - m);
        float inv = 1.f / (e0 + e1 + e2 + e3);
        *(float4*)&out[(size_t)node * 4] =
            make_float4(e0 * inv, e1 * inv, e2 * inv, e3 * inv);
    }
}

static inline int cdiv(long long a, int b) { return (int)((a + b - 1) / b); }

extern "C" void kernel_launch(void* const* d_in, const int* in_sizes, int n_in,
                              void* d_out, int out_size, void* d_ws, size_t ws_size,
                              hipStream_t stream) {
    const float* x   = (const float*)d_in[0];
    const int*   ei  = (const int*)d_in[1];
    const float* ew  = (const float*)d_in[2];
    const float* W1  = (const float*)d_in[3];
    const float* b1  = (const float*)d_in[4];
    const float* W2  = (const float*)d_in[5];
    const float* b2  = (const float*)d_in[6];
    const float* W3  = (const float*)d_in[7];
    const float* b3  = (const float*)d_in[8];
    float* out = (float*)d_out;

    const int N = in_sizes[0] / 128;
    const int E = in_sizes[2];
    const int* src = ei;
    const int* dst = ei + E;

    const int NB = (N + 255) >> 8;          // 391 buckets of 256 nodes
    const int GB = 256;
    const int CH = cdiv(E, GB);
    const int n_scan = NB * GB;             // 100,096

    char* base = (char*)d_ws;
    auto alloc = [&](size_t bytes) {
        char* p = base;
        base += (bytes + 255) & ~(size_t)255;
        return p;
    };
    float* dis      = (float*)alloc((size_t)N * 4);
    int*   row_ptr  = (int*)  alloc(((size_t)N + 1) * 4);
    int*   hist     = (int*)  alloc((size_t)n_scan * 4);
    int*   scanout  = (int*)  alloc((size_t)n_scan * 4);
    int*   partials = (int*)  alloc(512 * 4);
    uint*  pack     = (uint*) alloc((size_t)E * 4);
    char*  regA     = alloc((size_t)N * 64 * 4);   // tmp -> h3(f32)
    char*  regB     = alloc((size_t)N * 64 * 4);   // h2h (lo half) + h1h (hi half)
    int2*   tmp = (int2*)regA;
    float*  h3  = (float*)regA;                    // reuses regA after tmp dead
    ushort* h2h = (ushort*)regB;                   // [N,32] fp16, 6.4MB
    ushort* h1h = (ushort*)(regB + (size_t)N * 64 * 2);  // [N,64] fp16, upper half

    // --- merged hist + linear1 (independent of CSR build) ---
    k_hist_lin1<<<256 + cdiv(N, 64), 256, 0, stream>>>(
        dst, hist, E, CH, NB, x, W1, h1h, N);
    // --- CSR build via bucket sort ---
    k_scan1<<<cdiv(n_scan, 256), 256, 0, stream>>>(hist, scanout, partials, n_scan);
    k_scan2<<<1, 512, 0, stream>>>(partials, cdiv(n_scan, 256));
    k_bscatter<<<GB, 256, 0, stream>>>(src, dst, ew, scanout, partials, tmp, E, CH, NB);
    k_bcsr<<<NB, 256, 0, stream>>>(scanout, partials, tmp, pack, row_ptr, dis, N, E, NB);
    k_norm<<<cdiv(N, 4), 256, 0, stream>>>(row_ptr, dis, pack, N);

    // --- fused layers (h1/h2 fp16, h3 f32) ---
    fgather64<<<cdiv(N, 4), 256, 0, stream>>>(row_ptr, pack, dis, h1h, b1, W2, h2h, N);
    fgather32<<<cdiv(N, 4), 256, 0, stream>>>(row_ptr, pack, dis, h2h, b2, W3, h3, N);
    fgather4<<<cdiv(N, 8), 256, 0, stream>>>(row_ptr, pack, dis, h3, b3, out, N);
}